// Round 7
// baseline (167.871 us; speedup 1.0000x reference)
//
#include <hip/hip_runtime.h>

#define N_DOWN  50000
#define N_ABOVE 100000
#define DIM     256
#define FAN     5
#define K1      1280      // FAN * DIM
#define MPAD    100096    // 782 * 128

typedef __bf16 bf16x8 __attribute__((ext_vector_type(8)));
typedef float  f32x4  __attribute__((ext_vector_type(4)));

__device__ __forceinline__ unsigned short f2bf(float f) {
  unsigned u = __builtin_bit_cast(unsigned, f);
  u += 0x7FFFu + ((u >> 16) & 1u);          // RNE round to bf16
  return (unsigned short)(u >> 16);
}

__device__ __forceinline__ void gload16(const unsigned short* g, unsigned short* l) {
  __builtin_amdgcn_global_load_lds(
      (const __attribute__((address_space(1))) void*)g,
      (__attribute__((address_space(3))) void*)l, 16, 0, 0);
}

// ---- prep: h->bf16 convert + scatter + W1T/W2T transposes, one kernel ----
// (inv sentinel = -1 via hipMemsetAsync before this kernel; scatter overwrites)
// blocks [0,12500): h2bf; [12500,12696): scatter; [12696,12776): W1T; [12776,12792): W2T
__device__ __forceinline__ void transpose_tile(const float* __restrict__ in,
                                               unsigned short* __restrict__ out,
                                               int K, int N, int k0, int n0,
                                               float (*tile)[65]) {
  int c = threadIdx.x & 63, rb = threadIdx.x >> 6;
#pragma unroll
  for (int rr = 0; rr < 16; ++rr) {
    int row = rb + rr * 4;
    tile[row][c] = in[(size_t)(k0 + row) * N + n0 + c];
  }
  __syncthreads();
#pragma unroll
  for (int rr = 0; rr < 16; ++rr) {
    int nr = rb + rr * 4;
    out[(size_t)(n0 + nr) * K + k0 + c] = f2bf(tile[c][nr]);
  }
}

__global__ void k_prep_all(const float* __restrict__ h, const int* __restrict__ idx,
                           const float* __restrict__ W1, const float* __restrict__ W2,
                           int* __restrict__ inv, unsigned short* __restrict__ hbf,
                           unsigned short* __restrict__ w1t, unsigned short* __restrict__ w2t) {
  __shared__ float tile[64][65];
  const int b = blockIdx.x;
  if (b < 12500) {
    int t = b * 256 + threadIdx.x;                  // exactly 50000*256/4 float4s
    float4 v = ((const float4*)h)[t];
    ushort4 o;
    o.x = f2bf(v.x); o.y = f2bf(v.y); o.z = f2bf(v.z); o.w = f2bf(v.w);
    ((ushort4*)hbf)[t] = o;
  } else if (b < 12696) {
    int t = (b - 12500) * 256 + threadIdx.x;
    if (t < N_DOWN) inv[idx[t]] = t;
  } else if (b < 12776) {
    int bb = b - 12696;                             // 80 blocks: 20 k-tiles x 4 n-tiles
    transpose_tile(W1, w1t, K1, DIM, (bb % 20) * 64, (bb / 20) * 64, tile);
  } else {
    int bb = b - 12776;                             // 16 blocks: 4 x 4
    transpose_tile(W2, w2t, DIM, DIM, (bb % 4) * 64, (bb / 4) * 64, tile);
  }
}

// ---- GEMM1 (R1-verbatim structure, frozen at family ceiling ~813 TF) ----
__global__ __launch_bounds__(256, 2) void k_gemm1(
    const unsigned short* __restrict__ hbf,   // [N_DOWN+1][256] bf16
    const unsigned short* __restrict__ w1t,   // [256][1280]  bf16 (W1^T)
    const float* __restrict__ b1,
    const int* __restrict__ inv,              // [N_ABOVE], -1 = not a down node
    const int* __restrict__ jarr,             // [N_ABOVE*FAN]
    unsigned short* __restrict__ hid)         // [MPAD][256] bf16
{
  __shared__ __align__(16) unsigned short Alds[128 * 64];
  __shared__ __align__(16) unsigned short Blds[128 * 64];
  __shared__ unsigned short srcrow[128 * FAN];      // values <= N_DOWN (50000) fit u16

  const int tid = threadIdx.x;
  const int w = tid >> 6, l = tid & 63;
  const int m0 = blockIdx.x * 128, n0 = blockIdx.y * 128;
  const int wm = w >> 1, wn = w & 1;
  const int srow = l >> 3, slot = l & 7;

  for (int e = tid; e < 128 * FAN; e += 256) {
    int row = e / FAN, rr = e - row * FAN;
    int gm = m0 + row;
    int s = N_DOWN;
    if (gm < N_ABOVE) {
      s = inv[jarr[(size_t)gm * FAN + rr]];
      if (s < 0) s = N_DOWN;                        // memset sentinel -> zero row
    }
    srcrow[e] = (unsigned short)s;
  }

  f32x4 acc[4][4] = {};

  for (int t = 0; t < 20; ++t) {
    const int r = t >> 2;                      // fan-in segment
    __syncthreads();
#pragma unroll
    for (int i = 0; i < 4; ++i) {
      int row = w * 32 + i * 8 + srow;
      int src = srcrow[row * FAN + r];
      int c = slot ^ (row & 7);
      gload16(hbf + ((size_t)src << 8) + ((t & 3) << 6) + (c << 3),
              Alds + (w * 32 + i * 8) * 64);
    }
#pragma unroll
    for (int i = 0; i < 4; ++i) {
      int row = w * 32 + i * 8 + srow;
      int c = slot ^ (row & 7);
      gload16(w1t + (size_t)(n0 + row) * K1 + (t << 6) + (c << 3),
              Blds + (w * 32 + i * 8) * 64);
    }
    __syncthreads();

#pragma unroll
    for (int kk = 0; kk < 2; ++kk) {
      bf16x8 af[4], bfr[4];
#pragma unroll
      for (int m = 0; m < 4; ++m) {
        int row = wm * 64 + m * 16 + (l & 15);
        int c = (kk * 4 + (l >> 4)) ^ (row & 7);
        af[m] = *(const bf16x8*)(Alds + row * 64 + c * 8);
      }
#pragma unroll
      for (int n = 0; n < 4; ++n) {
        int row = wn * 64 + n * 16 + (l & 15);
        int c = (kk * 4 + (l >> 4)) ^ (row & 7);
        bfr[n] = *(const bf16x8*)(Blds + row * 64 + c * 8);
      }
#pragma unroll
      for (int m = 0; m < 4; ++m)
#pragma unroll
        for (int n = 0; n < 4; ++n)
          acc[m][n] = __builtin_amdgcn_mfma_f32_16x16x32_bf16(af[m], bfr[n], acc[m][n], 0, 0, 0);
    }
  }

  // epilogue: bias + relu -> bf16; nf innermost => 128B contiguous per 16-lane group
  float bias0 = b1[n0 + wn * 64 + 0 * 16 + (l & 15)];
  float bias1 = b1[n0 + wn * 64 + 1 * 16 + (l & 15)];
  float bias2 = b1[n0 + wn * 64 + 2 * 16 + (l & 15)];
  float bias3 = b1[n0 + wn * 64 + 3 * 16 + (l & 15)];
#pragma unroll
  for (int m = 0; m < 4; ++m) {
#pragma unroll
    for (int q = 0; q < 4; ++q) {
      int gm = m0 + wm * 64 + m * 16 + (l >> 4) * 4 + q;
#pragma unroll
      for (int n = 0; n < 4; ++n) {
        float bias = n == 0 ? bias0 : n == 1 ? bias1 : n == 2 ? bias2 : bias3;
        int gn = n0 + wn * 64 + n * 16 + (l & 15);
        float v = acc[m][n][q] + bias;
        v = v > 0.f ? v : 0.f;
        hid[(size_t)gm * DIM + gn] = f2bf(v);
      }
    }
  }
}

// ---- GEMM2: zero-LDS, zero-barrier direct-read (hid L3-resident, w2t L2-resident)
// out = hid @ W2 + b2, f32. 512 thr = 8 waves (2M x 4N), per-wave 64x64.
__global__ __launch_bounds__(512) void k_gemm2(
    const unsigned short* __restrict__ hid,   // [MPAD][256] bf16
    const unsigned short* __restrict__ w2t,   // [256][256] bf16 (W2^T)
    const float* __restrict__ b2,
    float* __restrict__ out)
{
  const int tid = threadIdx.x;
  const int w = tid >> 6, l = tid & 63;
  const int m0 = blockIdx.x * 128;
  const int wm = w >> 2, wn = w & 3;          // 2M x 4N waves, 64x64 each
  const int rowA = m0 + wm * 64 + (l & 15);   // + mf*16
  const int rowB = wn * 64 + (l & 15);        // + nf*16
  const int kb   = (l >> 4) * 8;              // k-offset within 32-chunk

  f32x4 acc[4][4] = {};
#pragma unroll 2
  for (int t = 0; t < 8; ++t) {
    bf16x8 af[4], bfr[4];
#pragma unroll
    for (int mf = 0; mf < 4; ++mf)
      af[mf] = *(const bf16x8*)(hid + (size_t)(rowA + mf * 16) * DIM + t * 32 + kb);
#pragma unroll
    for (int nf = 0; nf < 4; ++nf)
      bfr[nf] = *(const bf16x8*)(w2t + (size_t)(rowB + nf * 16) * DIM + t * 32 + kb);
#pragma unroll
    for (int mf = 0; mf < 4; ++mf)
#pragma unroll
      for (int nf = 0; nf < 4; ++nf)
        acc[mf][nf] = __builtin_amdgcn_mfma_f32_16x16x32_bf16(af[mf], bfr[nf], acc[mf][nf], 0, 0, 0);
  }

  // epilogue: bias -> f32; nf innermost => 256B contiguous per 16-lane group
  float bias0 = b2[wn * 64 + 0 * 16 + (l & 15)];
  float bias1 = b2[wn * 64 + 1 * 16 + (l & 15)];
  float bias2 = b2[wn * 64 + 2 * 16 + (l & 15)];
  float bias3 = b2[wn * 64 + 3 * 16 + (l & 15)];
#pragma unroll
  for (int m = 0; m < 4; ++m) {
#pragma unroll
    for (int q = 0; q < 4; ++q) {
      int gm = m0 + wm * 64 + m * 16 + (l >> 4) * 4 + q;
      if (gm < N_ABOVE) {
#pragma unroll
        for (int n = 0; n < 4; ++n) {
          float bias = n == 0 ? bias0 : n == 1 ? bias1 : n == 2 ? bias2 : bias3;
          int gn = wn * 64 + n * 16 + (l & 15);
          out[(size_t)gm * DIM + gn] = acc[m][n][q] + bias;
        }
      }
    }
  }
}

extern "C" void kernel_launch(void* const* d_in, const int* in_sizes, int n_in,
                              void* d_out, int out_size, void* d_ws, size_t ws_size,
                              hipStream_t stream) {
  const float* h    = (const float*)d_in[0];
  const int*   idx  = (const int*)d_in[2];
  const int*   jarr = (const int*)d_in[4];
  const float* W1   = (const float*)d_in[5];
  const float* b1   = (const float*)d_in[6];
  const float* W2   = (const float*)d_in[7];
  const float* b2   = (const float*)d_in[8];
  float* out = (float*)d_out;

  char* ws = (char*)d_ws;
  size_t off = 0;
  auto alloc = [&](size_t bytes) -> void* {
    void* p = ws + off;
    off += bytes;
    off = (off + 511) & ~(size_t)511;
    return p;
  };
  int*            inv = (int*)alloc((size_t)N_ABOVE * 4);
  unsigned short* hbf = (unsigned short*)alloc((size_t)(N_DOWN + 1) * DIM * 2);
  unsigned short* w1t = (unsigned short*)alloc((size_t)DIM * K1 * 2);
  unsigned short* w2t = (unsigned short*)alloc((size_t)DIM * DIM * 2);
  unsigned short* hid = (unsigned short*)alloc((size_t)MPAD * DIM * 2);
  if (ws_size < off) return;

  hipMemsetAsync(inv, 0xFF, (size_t)N_ABOVE * 4, stream);               // inv[u] = -1
  hipMemsetAsync(hbf + (size_t)N_DOWN * DIM, 0, DIM * 2, stream);       // zero row
  k_prep_all<<<dim3(12792), dim3(256), 0, stream>>>(h, idx, W1, W2, inv, hbf, w1t, w2t);
  k_gemm1<<<dim3(MPAD / 128, 2), dim3(256), 0, stream>>>(hbf, w1t, b1, inv, jarr, hid);
  k_gemm2<<<dim3(MPAD / 128), dim3(512), 0, stream>>>(hid, w2t, b2, out);
}

// Round 8
// 128.209 us; speedup vs baseline: 1.3094x; 1.3094x over previous
//
#include <hip/hip_runtime.h>

#define N_DOWN  50000
#define N_ABOVE 100000
#define DIM     256
#define FAN     5
#define K1      1280      // FAN * DIM
#define MPAD    100096    // 782 * 128

typedef __bf16 bf16x8 __attribute__((ext_vector_type(8)));
typedef float  f32x4  __attribute__((ext_vector_type(4)));

__device__ __forceinline__ unsigned short f2bf(float f) {
  unsigned u = __builtin_bit_cast(unsigned, f);
  u += 0x7FFFu + ((u >> 16) & 1u);          // RNE round to bf16
  return (unsigned short)(u >> 16);
}

__device__ __forceinline__ void gload16(const unsigned short* g, unsigned short* l) {
  __builtin_amdgcn_global_load_lds(
      (const __attribute__((address_space(1))) void*)g,
      (__attribute__((address_space(3))) void*)l, 16, 0, 0);
}

// ---- prep: h->bf16 convert + scatter + W1T/W2T transposes, one kernel ----
// (inv sentinel = -1 via hipMemsetAsync before this kernel; scatter overwrites)
// blocks [0,12500): h2bf; [12500,12696): scatter; [12696,12776): W1T; [12776,12792): W2T
__device__ __forceinline__ void transpose_tile(const float* __restrict__ in,
                                               unsigned short* __restrict__ out,
                                               int K, int N, int k0, int n0,
                                               float (*tile)[65]) {
  int c = threadIdx.x & 63, rb = threadIdx.x >> 6;
#pragma unroll
  for (int rr = 0; rr < 16; ++rr) {
    int row = rb + rr * 4;
    tile[row][c] = in[(size_t)(k0 + row) * N + n0 + c];
  }
  __syncthreads();
#pragma unroll
  for (int rr = 0; rr < 16; ++rr) {
    int nr = rb + rr * 4;
    out[(size_t)(n0 + nr) * K + k0 + c] = f2bf(tile[c][nr]);
  }
}

__global__ void k_prep_all(const float* __restrict__ h, const int* __restrict__ idx,
                           const float* __restrict__ W1, const float* __restrict__ W2,
                           int* __restrict__ inv, unsigned short* __restrict__ hbf,
                           unsigned short* __restrict__ w1t, unsigned short* __restrict__ w2t) {
  __shared__ float tile[64][65];
  const int b = blockIdx.x;
  if (b < 12500) {
    int t = b * 256 + threadIdx.x;                  // exactly 50000*256/4 float4s
    float4 v = ((const float4*)h)[t];
    ushort4 o;
    o.x = f2bf(v.x); o.y = f2bf(v.y); o.z = f2bf(v.z); o.w = f2bf(v.w);
    ((ushort4*)hbf)[t] = o;
  } else if (b < 12696) {
    int t = (b - 12500) * 256 + threadIdx.x;
    if (t < N_DOWN) inv[idx[t]] = t;
  } else if (b < 12776) {
    int bb = b - 12696;                             // 80 blocks: 20 k-tiles x 4 n-tiles
    transpose_tile(W1, w1t, K1, DIM, (bb % 20) * 64, (bb / 20) * 64, tile);
  } else {
    int bb = b - 12776;                             // 16 blocks: 4 x 4
    transpose_tile(W2, w2t, DIM, DIM, (bb % 4) * 64, (bb / 4) * 64, tile);
  }
}

// ---- GEMM1 (2-barrier family, BN=256 1D-grid): hid = relu(gather(hbf)@W1 + b1)
// 512 thr = 8 waves (2M x 4N), per-wave 64x64. A gathered ONCE per m-tile.
__global__ __launch_bounds__(512, 2) void k_gemm1(
    const unsigned short* __restrict__ hbf,   // [N_DOWN+1][256] bf16
    const unsigned short* __restrict__ w1t,   // [256][1280]  bf16 (W1^T)
    const float* __restrict__ b1,
    const int* __restrict__ inv,              // [N_ABOVE], -1 = not a down node
    const int* __restrict__ jarr,             // [N_ABOVE*FAN]
    unsigned short* __restrict__ hid)         // [MPAD][256] bf16
{
  __shared__ __align__(16) unsigned short Alds[128 * 64];   // 16 KB
  __shared__ __align__(16) unsigned short Blds[256 * 64];   // 32 KB
  __shared__ unsigned short srcrow[128 * FAN];              // 1.25 KB, vals <= 50000

  const int tid = threadIdx.x;
  const int w = tid >> 6, l = tid & 63;
  const int m0 = blockIdx.x * 128;
  const int wm = w >> 2, wn = w & 3;          // 2M x 4N waves, 64x64 each
  const int srow = l >> 3, slot = l & 7;

  for (int e = tid; e < 128 * FAN; e += 512) {
    int row = e / FAN, rr = e - row * FAN;
    int gm = m0 + row;
    int s = N_DOWN;
    if (gm < N_ABOVE) {
      s = inv[jarr[(size_t)gm * FAN + rr]];
      if (s < 0) s = N_DOWN;                        // memset sentinel -> zero row
    }
    srcrow[e] = (unsigned short)s;
  }

  f32x4 acc[4][4] = {};

  for (int t = 0; t < 20; ++t) {
    const int r = t >> 2;                      // fan-in segment
    __syncthreads();
#pragma unroll
    for (int i = 0; i < 2; ++i) {              // stage A: 128 rows
      int row = w * 16 + i * 8 + srow;
      int src = srcrow[row * FAN + r];
      int c = slot ^ (row & 7);
      gload16(hbf + ((size_t)src << 8) + ((t & 3) << 6) + (c << 3),
              Alds + (w * 16 + i * 8) * 64);
    }
#pragma unroll
    for (int i = 0; i < 4; ++i) {              // stage B: 256 rows
      int row = w * 32 + i * 8 + srow;
      int c = slot ^ (row & 7);
      gload16(w1t + (size_t)row * K1 + (t << 6) + (c << 3),
              Blds + (w * 32 + i * 8) * 64);
    }
    __syncthreads();

#pragma unroll
    for (int kk = 0; kk < 2; ++kk) {
      bf16x8 af[4], bfr[4];
#pragma unroll
      for (int m = 0; m < 4; ++m) {
        int row = wm * 64 + m * 16 + (l & 15);
        int c = (kk * 4 + (l >> 4)) ^ (row & 7);
        af[m] = *(const bf16x8*)(Alds + row * 64 + c * 8);
      }
#pragma unroll
      for (int n = 0; n < 4; ++n) {
        int row = wn * 64 + n * 16 + (l & 15);
        int c = (kk * 4 + (l >> 4)) ^ (row & 7);
        bfr[n] = *(const bf16x8*)(Blds + row * 64 + c * 8);
      }
#pragma unroll
      for (int m = 0; m < 4; ++m)
#pragma unroll
        for (int n = 0; n < 4; ++n)
          acc[m][n] = __builtin_amdgcn_mfma_f32_16x16x32_bf16(af[m], bfr[n], acc[m][n], 0, 0, 0);
    }
  }

  // epilogue: bias + relu -> bf16; nf innermost => 128B contiguous per 16-lane group
  float bias0 = b1[wn * 64 + 0 * 16 + (l & 15)];
  float bias1 = b1[wn * 64 + 1 * 16 + (l & 15)];
  float bias2 = b1[wn * 64 + 2 * 16 + (l & 15)];
  float bias3 = b1[wn * 64 + 3 * 16 + (l & 15)];
#pragma unroll
  for (int m = 0; m < 4; ++m) {
#pragma unroll
    for (int q = 0; q < 4; ++q) {
      int gm = m0 + wm * 64 + m * 16 + (l >> 4) * 4 + q;
#pragma unroll
      for (int n = 0; n < 4; ++n) {
        float bias = n == 0 ? bias0 : n == 1 ? bias1 : n == 2 ? bias2 : bias3;
        int gn = wn * 64 + n * 16 + (l & 15);
        float v = acc[m][n][q] + bias;
        v = v > 0.f ? v : 0.f;
        hid[(size_t)gm * DIM + gn] = f2bf(v);
      }
    }
  }
}

// ---- GEMM2 (R6-verbatim: BN=256, 512 thr, hid read ONCE): out = hid @ W2 + b2 ----
__global__ __launch_bounds__(512, 2) void k_gemm2(
    const unsigned short* __restrict__ hid,   // [MPAD][256] bf16
    const unsigned short* __restrict__ w2t,   // [256][256] bf16 (W2^T)
    const float* __restrict__ b2,
    float* __restrict__ out)
{
  __shared__ __align__(16) unsigned short Alds[128 * 64];   // 16 KB
  __shared__ __align__(16) unsigned short Blds[256 * 64];   // 32 KB

  const int tid = threadIdx.x;
  const int w = tid >> 6, l = tid & 63;
  const int m0 = blockIdx.x * 128;
  const int wm = w >> 2, wn = w & 3;          // 2M x 4N waves, 64x64 each
  const int srow = l >> 3, slot = l & 7;

  f32x4 acc[4][4] = {};

  for (int t = 0; t < 4; ++t) {
    __syncthreads();
#pragma unroll
    for (int i = 0; i < 2; ++i) {             // A: 128 rows
      int row = w * 16 + i * 8 + srow;
      int c = slot ^ (row & 7);
      gload16(hid + (size_t)(m0 + row) * DIM + (t << 6) + (c << 3),
              Alds + (w * 16 + i * 8) * 64);
    }
#pragma unroll
    for (int i = 0; i < 4; ++i) {             // B: 256 rows
      int row = w * 32 + i * 8 + srow;
      int c = slot ^ (row & 7);
      gload16(w2t + (size_t)row * DIM + (t << 6) + (c << 3),
              Blds + (w * 32 + i * 8) * 64);
    }
    __syncthreads();

#pragma unroll
    for (int kk = 0; kk < 2; ++kk) {
      bf16x8 af[4], bfr[4];
#pragma unroll
      for (int m = 0; m < 4; ++m) {
        int row = wm * 64 + m * 16 + (l & 15);
        int c = (kk * 4 + (l >> 4)) ^ (row & 7);
        af[m] = *(const bf16x8*)(Alds + row * 64 + c * 8);
      }
#pragma unroll
      for (int n = 0; n < 4; ++n) {
        int row = wn * 64 + n * 16 + (l & 15);
        int c = (kk * 4 + (l >> 4)) ^ (row & 7);
        bfr[n] = *(const bf16x8*)(Blds + row * 64 + c * 8);
      }
#pragma unroll
      for (int m = 0; m < 4; ++m)
#pragma unroll
        for (int n = 0; n < 4; ++n)
          acc[m][n] = __builtin_amdgcn_mfma_f32_16x16x32_bf16(af[m], bfr[n], acc[m][n], 0, 0, 0);
    }
  }

  // epilogue: bias -> f32; nf innermost => 256B contiguous per 16-lane group
  float bias0 = b2[wn * 64 + 0 * 16 + (l & 15)];
  float bias1 = b2[wn * 64 + 1 * 16 + (l & 15)];
  float bias2 = b2[wn * 64 + 2 * 16 + (l & 15)];
  float bias3 = b2[wn * 64 + 3 * 16 + (l & 15)];
#pragma unroll
  for (int m = 0; m < 4; ++m) {
#pragma unroll
    for (int q = 0; q < 4; ++q) {
      int gm = m0 + wm * 64 + m * 16 + (l >> 4) * 4 + q;
      if (gm < N_ABOVE) {
#pragma unroll
        for (int n = 0; n < 4; ++n) {
          float bias = n == 0 ? bias0 : n == 1 ? bias1 : n == 2 ? bias2 : bias3;
          int gn = wn * 64 + n * 16 + (l & 15);
          out[(size_t)gm * DIM + gn] = acc[m][n][q] + bias;
        }
      }
    }
  }
}

extern "C" void kernel_launch(void* const* d_in, const int* in_sizes, int n_in,
                              void* d_out, int out_size, void* d_ws, size_t ws_size,
                              hipStream_t stream) {
  const float* h    = (const float*)d_in[0];
  const int*   idx  = (const int*)d_in[2];
  const int*   jarr = (const int*)d_in[4];
  const float* W1   = (const float*)d_in[5];
  const float* b1   = (const float*)d_in[6];
  const float* W2   = (const float*)d_in[7];
  const float* b2   = (const float*)d_in[8];
  float* out = (float*)d_out;

  char* ws = (char*)d_ws;
  size_t off = 0;
  auto alloc = [&](size_t bytes) -> void* {
    void* p = ws + off;
    off += bytes;
    off = (off + 511) & ~(size_t)511;
    return p;
  };
  int*            inv = (int*)alloc((size_t)N_ABOVE * 4);
  unsigned short* hbf = (unsigned short*)alloc((size_t)(N_DOWN + 1) * DIM * 2);
  unsigned short* w1t = (unsigned short*)alloc((size_t)DIM * K1 * 2);
  unsigned short* w2t = (unsigned short*)alloc((size_t)DIM * DIM * 2);
  unsigned short* hid = (unsigned short*)alloc((size_t)MPAD * DIM * 2);
  if (ws_size < off) return;

  hipMemsetAsync(inv, 0xFF, (size_t)N_ABOVE * 4, stream);               // inv[u] = -1
  hipMemsetAsync(hbf + (size_t)N_DOWN * DIM, 0, DIM * 2, stream);       // zero row
  k_prep_all<<<dim3(12792), dim3(256), 0, stream>>>(h, idx, W1, W2, inv, hbf, w1t, w2t);
  k_gemm1<<<dim3(MPAD / 128), dim3(512), 0, stream>>>(hbf, w1t, b1, inv, jarr, hid);
  k_gemm2<<<dim3(MPAD / 128), dim3(512), 0, stream>>>(hid, w2t, b2, out);
}

// Round 9
// 127.010 us; speedup vs baseline: 1.3217x; 1.0094x over previous
//
#include <hip/hip_runtime.h>

#define N_DOWN  50000
#define N_ABOVE 100000
#define DIM     256
#define FAN     5
#define K1      1280      // FAN * DIM
#define MPAD    100096    // 782 * 128

typedef __bf16 bf16x8 __attribute__((ext_vector_type(8)));
typedef float  f32x4  __attribute__((ext_vector_type(4)));

__device__ __forceinline__ unsigned short f2bf(float f) {
  unsigned u = __builtin_bit_cast(unsigned, f);
  u += 0x7FFFu + ((u >> 16) & 1u);          // RNE round to bf16
  return (unsigned short)(u >> 16);
}

__device__ __forceinline__ void gload16(const unsigned short* g, unsigned short* l) {
  __builtin_amdgcn_global_load_lds(
      (const __attribute__((address_space(1))) void*)g,
      (__attribute__((address_space(3))) void*)l, 16, 0, 0);
}

// ---- prep: h->bf16 + scatter + W1T/W2T transposes, one kernel ----
// (inv sentinel = -1 via hipMemsetAsync before this kernel; scatter overwrites.
//  hbf zero-row via memset.)
// blocks [0,12500): h2bf; [12500,12696): scatter; [12696,12776): W1T; [12776,12792): W2T
__device__ __forceinline__ void transpose_tile(const float* __restrict__ in,
                                               unsigned short* __restrict__ out,
                                               int K, int N, int k0, int n0,
                                               float (*tile)[65]) {
  int c = threadIdx.x & 63, rb = threadIdx.x >> 6;
#pragma unroll
  for (int rr = 0; rr < 16; ++rr) {
    int row = rb + rr * 4;
    tile[row][c] = in[(size_t)(k0 + row) * N + n0 + c];
  }
  __syncthreads();
#pragma unroll
  for (int rr = 0; rr < 16; ++rr) {
    int nr = rb + rr * 4;
    out[(size_t)(n0 + nr) * K + k0 + c] = f2bf(tile[c][nr]);
  }
}

__global__ void k_prep_all(const float* __restrict__ h, const int* __restrict__ idx,
                           const float* __restrict__ W1, const float* __restrict__ W2,
                           int* __restrict__ inv, unsigned short* __restrict__ hbf,
                           unsigned short* __restrict__ w1t, unsigned short* __restrict__ w2t) {
  __shared__ float tile[64][65];
  const int b = blockIdx.x;
  if (b < 12500) {
    int t = b * 256 + threadIdx.x;                  // exactly 50000*256/4 float4s
    float4 v = ((const float4*)h)[t];
    ushort4 o;
    o.x = f2bf(v.x); o.y = f2bf(v.y); o.z = f2bf(v.z); o.w = f2bf(v.w);
    ((ushort4*)hbf)[t] = o;
  } else if (b < 12696) {
    int t = (b - 12500) * 256 + threadIdx.x;
    if (t < N_DOWN) inv[idx[t]] = t;
  } else if (b < 12776) {
    int bb = b - 12696;                             // 80 blocks: 20 k-tiles x 4 n-tiles
    transpose_tile(W1, w1t, K1, DIM, (bb % 20) * 64, (bb / 20) * 64, tile);
  } else {
    int bb = b - 12776;                             // 16 blocks: 4 x 4
    transpose_tile(W2, w2t, DIM, DIM, (bb % 4) * 64, (bb / 4) * 64, tile);
  }
}

// ---- GEMM1 (measured family optimum: grid (782,2), 256 thr, 4 waves, 35 KB LDS)
// hid = relu(gather(hbf) @ W1 + b1), bf16 out
__global__ __launch_bounds__(256, 2) void k_gemm1(
    const unsigned short* __restrict__ hbf,   // [N_DOWN+1][256] bf16
    const unsigned short* __restrict__ w1t,   // [256][1280]  bf16 (W1^T)
    const float* __restrict__ b1,
    const int* __restrict__ inv,              // [N_ABOVE], -1 = not a down node
    const int* __restrict__ jarr,             // [N_ABOVE*FAN]
    unsigned short* __restrict__ hid)         // [MPAD][256] bf16
{
  __shared__ __align__(16) unsigned short Alds[128 * 64];
  __shared__ __align__(16) unsigned short Blds[128 * 64];
  __shared__ unsigned short srcrow[128 * FAN];      // values <= N_DOWN (50000) fit u16

  const int tid = threadIdx.x;
  const int w = tid >> 6, l = tid & 63;
  const int m0 = blockIdx.x * 128, n0 = blockIdx.y * 128;
  const int wm = w >> 1, wn = w & 1;
  const int srow = l >> 3, slot = l & 7;

  for (int e = tid; e < 128 * FAN; e += 256) {
    int row = e / FAN, rr = e - row * FAN;
    int gm = m0 + row;
    int s = N_DOWN;
    if (gm < N_ABOVE) {
      s = inv[jarr[(size_t)gm * FAN + rr]];
      if (s < 0) s = N_DOWN;                        // memset sentinel -> zero row
    }
    srcrow[e] = (unsigned short)s;
  }

  f32x4 acc[4][4] = {};

  for (int t = 0; t < 20; ++t) {
    const int r = t >> 2;                      // fan-in segment
    __syncthreads();
#pragma unroll
    for (int i = 0; i < 4; ++i) {
      int row = w * 32 + i * 8 + srow;
      int src = srcrow[row * FAN + r];
      int c = slot ^ (row & 7);
      gload16(hbf + ((size_t)src << 8) + ((t & 3) << 6) + (c << 3),
              Alds + (w * 32 + i * 8) * 64);
    }
#pragma unroll
    for (int i = 0; i < 4; ++i) {
      int row = w * 32 + i * 8 + srow;
      int c = slot ^ (row & 7);
      gload16(w1t + (size_t)(n0 + row) * K1 + (t << 6) + (c << 3),
              Blds + (w * 32 + i * 8) * 64);
    }
    __syncthreads();

#pragma unroll
    for (int kk = 0; kk < 2; ++kk) {
      bf16x8 af[4], bfr[4];
#pragma unroll
      for (int m = 0; m < 4; ++m) {
        int row = wm * 64 + m * 16 + (l & 15);
        int c = (kk * 4 + (l >> 4)) ^ (row & 7);
        af[m] = *(const bf16x8*)(Alds + row * 64 + c * 8);
      }
#pragma unroll
      for (int n = 0; n < 4; ++n) {
        int row = wn * 64 + n * 16 + (l & 15);
        int c = (kk * 4 + (l >> 4)) ^ (row & 7);
        bfr[n] = *(const bf16x8*)(Blds + row * 64 + c * 8);
      }
#pragma unroll
      for (int m = 0; m < 4; ++m)
#pragma unroll
        for (int n = 0; n < 4; ++n)
          acc[m][n] = __builtin_amdgcn_mfma_f32_16x16x32_bf16(af[m], bfr[n], acc[m][n], 0, 0, 0);
    }
  }

  // epilogue: bias + relu -> bf16; n innermost => 128B contiguous per 16-lane group
  float bias0 = b1[n0 + wn * 64 + 0 * 16 + (l & 15)];
  float bias1 = b1[n0 + wn * 64 + 1 * 16 + (l & 15)];
  float bias2 = b1[n0 + wn * 64 + 2 * 16 + (l & 15)];
  float bias3 = b1[n0 + wn * 64 + 3 * 16 + (l & 15)];
#pragma unroll
  for (int m = 0; m < 4; ++m) {
#pragma unroll
    for (int q = 0; q < 4; ++q) {
      int gm = m0 + wm * 64 + m * 16 + (l >> 4) * 4 + q;
#pragma unroll
      for (int n = 0; n < 4; ++n) {
        float bias = n == 0 ? bias0 : n == 1 ? bias1 : n == 2 ? bias2 : bias3;
        int gn = n0 + wn * 64 + n * 16 + (l & 15);
        float v = acc[m][n][q] + bias;
        v = v > 0.f ? v : 0.f;
        hid[(size_t)gm * DIM + gn] = f2bf(v);
      }
    }
  }
}

// ---- GEMM2 (R6-verbatim: BN=256, 512 thr, hid read ONCE): out = hid @ W2 + b2 ----
__global__ __launch_bounds__(512, 2) void k_gemm2(
    const unsigned short* __restrict__ hid,   // [MPAD][256] bf16
    const unsigned short* __restrict__ w2t,   // [256][256] bf16 (W2^T)
    const float* __restrict__ b2,
    float* __restrict__ out)
{
  __shared__ __align__(16) unsigned short Alds[128 * 64];   // 16 KB
  __shared__ __align__(16) unsigned short Blds[256 * 64];   // 32 KB

  const int tid = threadIdx.x;
  const int w = tid >> 6, l = tid & 63;
  const int m0 = blockIdx.x * 128;
  const int wm = w >> 2, wn = w & 3;          // 2M x 4N waves, 64x64 each
  const int srow = l >> 3, slot = l & 7;

  f32x4 acc[4][4] = {};

  for (int t = 0; t < 4; ++t) {
    __syncthreads();
#pragma unroll
    for (int i = 0; i < 2; ++i) {             // A: 128 rows
      int row = w * 16 + i * 8 + srow;
      int c = slot ^ (row & 7);
      gload16(hid + (size_t)(m0 + row) * DIM + (t << 6) + (c << 3),
              Alds + (w * 16 + i * 8) * 64);
    }
#pragma unroll
    for (int i = 0; i < 4; ++i) {             // B: 256 rows
      int row = w * 32 + i * 8 + srow;
      int c = slot ^ (row & 7);
      gload16(w2t + (size_t)row * DIM + (t << 6) + (c << 3),
              Blds + (w * 32 + i * 8) * 64);
    }
    __syncthreads();

#pragma unroll
    for (int kk = 0; kk < 2; ++kk) {
      bf16x8 af[4], bfr[4];
#pragma unroll
      for (int m = 0; m < 4; ++m) {
        int row = wm * 64 + m * 16 + (l & 15);
        int c = (kk * 4 + (l >> 4)) ^ (row & 7);
        af[m] = *(const bf16x8*)(Alds + row * 64 + c * 8);
      }
#pragma unroll
      for (int n = 0; n < 4; ++n) {
        int row = wn * 64 + n * 16 + (l & 15);
        int c = (kk * 4 + (l >> 4)) ^ (row & 7);
        bfr[n] = *(const bf16x8*)(Blds + row * 64 + c * 8);
      }
#pragma unroll
      for (int m = 0; m < 4; ++m)
#pragma unroll
        for (int n = 0; n < 4; ++n)
          acc[m][n] = __builtin_amdgcn_mfma_f32_16x16x32_bf16(af[m], bfr[n], acc[m][n], 0, 0, 0);
    }
  }

  // epilogue: bias -> f32; n innermost => 256B contiguous per 16-lane group
  float bias0 = b2[wn * 64 + 0 * 16 + (l & 15)];
  float bias1 = b2[wn * 64 + 1 * 16 + (l & 15)];
  float bias2 = b2[wn * 64 + 2 * 16 + (l & 15)];
  float bias3 = b2[wn * 64 + 3 * 16 + (l & 15)];
#pragma unroll
  for (int m = 0; m < 4; ++m) {
#pragma unroll
    for (int q = 0; q < 4; ++q) {
      int gm = m0 + wm * 64 + m * 16 + (l >> 4) * 4 + q;
      if (gm < N_ABOVE) {
#pragma unroll
        for (int n = 0; n < 4; ++n) {
          float bias = n == 0 ? bias0 : n == 1 ? bias1 : n == 2 ? bias2 : bias3;
          int gn = wn * 64 + n * 16 + (l & 15);
          out[(size_t)gm * DIM + gn] = acc[m][n][q] + bias;
        }
      }
    }
  }
}

extern "C" void kernel_launch(void* const* d_in, const int* in_sizes, int n_in,
                              void* d_out, int out_size, void* d_ws, size_t ws_size,
                              hipStream_t stream) {
  const float* h    = (const float*)d_in[0];
  const int*   idx  = (const int*)d_in[2];
  const int*   jarr = (const int*)d_in[4];
  const float* W1   = (const float*)d_in[5];
  const float* b1   = (const float*)d_in[6];
  const float* W2   = (const float*)d_in[7];
  const float* b2   = (const float*)d_in[8];
  float* out = (float*)d_out;

  char* ws = (char*)d_ws;
  size_t off = 0;
  auto alloc = [&](size_t bytes) -> void* {
    void* p = ws + off;
    off += bytes;
    off = (off + 511) & ~(size_t)511;
    return p;
  };
  int*            inv = (int*)alloc((size_t)N_ABOVE * 4);
  unsigned short* hbf = (unsigned short*)alloc((size_t)(N_DOWN + 1) * DIM * 2);
  unsigned short* w1t = (unsigned short*)alloc((size_t)DIM * K1 * 2);
  unsigned short* w2t = (unsigned short*)alloc((size_t)DIM * DIM * 2);
  unsigned short* hid = (unsigned short*)alloc((size_t)MPAD * DIM * 2);
  if (ws_size < off) return;

  hipMemsetAsync(inv, 0xFF, (size_t)N_ABOVE * 4, stream);               // inv[u] = -1
  hipMemsetAsync(hbf + (size_t)N_DOWN * DIM, 0, DIM * 2, stream);       // zero row
  k_prep_all<<<dim3(12792), dim3(256), 0, stream>>>(h, idx, W1, W2, inv, hbf, w1t, w2t);
  k_gemm1<<<dim3(MPAD / 128, 2), dim3(256), 0, stream>>>(hbf, w1t, b1, inv, jarr, hid);
  k_gemm2<<<dim3(MPAD / 128), dim3(512), 0, stream>>>(hid, w2t, b2, out);
}

// Round 10
// 124.423 us; speedup vs baseline: 1.3492x; 1.0208x over previous
//
#include <hip/hip_runtime.h>

#define N_DOWN  50000
#define N_ABOVE 100000
#define DIM     256
#define FAN     5
#define K1      1280      // FAN * DIM
#define MPAD    100096    // 782 * 128

typedef __bf16 bf16x8 __attribute__((ext_vector_type(8)));
typedef float  f32x4  __attribute__((ext_vector_type(4)));

__device__ __forceinline__ unsigned short f2bf(float f) {
  unsigned u = __builtin_bit_cast(unsigned, f);
  u += 0x7FFFu + ((u >> 16) & 1u);          // RNE round to bf16
  return (unsigned short)(u >> 16);
}

__device__ __forceinline__ void gload16(const unsigned short* g, unsigned short* l) {
  __builtin_amdgcn_global_load_lds(
      (const __attribute__((address_space(1))) void*)g,
      (__attribute__((address_space(3))) void*)l, 16, 0, 0);
}

// ---- prep 1: inv sentinel + zero row (must precede scatter) ----
__global__ void k_prep_inv(int* __restrict__ inv, unsigned short* __restrict__ hbf) {
  int t = blockIdx.x * 256 + threadIdx.x;
  if (t < N_ABOVE) inv[t] = N_DOWN;                 // sentinel -> zero row
  if (t < DIM)     hbf[(size_t)N_DOWN * DIM + t] = 0;
}

// ---- prep 2: h->bf16 convert + scatter + W1T/W2T transposes, one kernel ----
// blocks [0,12500): h2bf; [12500,12696): scatter; [12696,12776): W1T; [12776,12792): W2T
__device__ __forceinline__ void transpose_tile(const float* __restrict__ in,
                                               unsigned short* __restrict__ out,
                                               int K, int N, int k0, int n0,
                                               float (*tile)[65]) {
  int c = threadIdx.x & 63, rb = threadIdx.x >> 6;
#pragma unroll
  for (int rr = 0; rr < 16; ++rr) {
    int row = rb + rr * 4;
    tile[row][c] = in[(size_t)(k0 + row) * N + n0 + c];
  }
  __syncthreads();
#pragma unroll
  for (int rr = 0; rr < 16; ++rr) {
    int nr = rb + rr * 4;
    out[(size_t)(n0 + nr) * K + k0 + c] = f2bf(tile[c][nr]);
  }
}

__global__ void k_prep_all(const float* __restrict__ h, const int* __restrict__ idx,
                           const float* __restrict__ W1, const float* __restrict__ W2,
                           int* __restrict__ inv, unsigned short* __restrict__ hbf,
                           unsigned short* __restrict__ w1t, unsigned short* __restrict__ w2t) {
  __shared__ float tile[64][65];
  const int b = blockIdx.x;
  if (b < 12500) {
    int t = b * 256 + threadIdx.x;                  // exactly 50000*256/4 float4s
    float4 v = ((const float4*)h)[t];
    ushort4 o;
    o.x = f2bf(v.x); o.y = f2bf(v.y); o.z = f2bf(v.z); o.w = f2bf(v.w);
    ((ushort4*)hbf)[t] = o;
  } else if (b < 12696) {
    int t = (b - 12500) * 256 + threadIdx.x;
    if (t < N_DOWN) inv[idx[t]] = t;
  } else if (b < 12776) {
    int bb = b - 12696;                             // 80 blocks: 20 k-tiles x 4 n-tiles
    transpose_tile(W1, w1t, K1, DIM, (bb % 20) * 64, (bb / 20) * 64, tile);
  } else {
    int bb = b - 12776;                             // 16 blocks: 4 x 4
    transpose_tile(W2, w2t, DIM, DIM, (bb % 4) * 64, (bb / 4) * 64, tile);
  }
}

// ---- GEMM1 (measured family optimum: grid (782,2), 256 thr, 4 waves, 35 KB LDS)
// hid = relu(gather(hbf) @ W1 + b1), bf16 out
__global__ __launch_bounds__(256, 2) void k_gemm1(
    const unsigned short* __restrict__ hbf,   // [N_DOWN+1][256] bf16
    const unsigned short* __restrict__ w1t,   // [256][1280]  bf16 (W1^T)
    const float* __restrict__ b1,
    const int* __restrict__ inv,              // [N_ABOVE]
    const int* __restrict__ jarr,             // [N_ABOVE*FAN]
    unsigned short* __restrict__ hid)         // [MPAD][256] bf16
{
  __shared__ __align__(16) unsigned short Alds[128 * 64];
  __shared__ __align__(16) unsigned short Blds[128 * 64];
  __shared__ int srcrow[128 * FAN];

  const int tid = threadIdx.x;
  const int w = tid >> 6, l = tid & 63;
  const int m0 = blockIdx.x * 128, n0 = blockIdx.y * 128;
  const int wm = w >> 1, wn = w & 1;
  const int srow = l >> 3, slot = l & 7;

  for (int e = tid; e < 128 * FAN; e += 256) {
    int row = e / FAN, rr = e - row * FAN;
    int gm = m0 + row;
    int s = N_DOWN;
    if (gm < N_ABOVE) s = inv[jarr[(size_t)gm * FAN + rr]];
    srcrow[e] = s;
  }

  f32x4 acc[4][4] = {};

  for (int t = 0; t < 20; ++t) {
    const int r = t >> 2;                      // fan-in segment
    __syncthreads();
#pragma unroll
    for (int i = 0; i < 4; ++i) {
      int row = w * 32 + i * 8 + srow;
      int src = srcrow[row * FAN + r];
      int c = slot ^ (row & 7);
      gload16(hbf + ((size_t)src << 8) + ((t & 3) << 6) + (c << 3),
              Alds + (w * 32 + i * 8) * 64);
    }
#pragma unroll
    for (int i = 0; i < 4; ++i) {
      int row = w * 32 + i * 8 + srow;
      int c = slot ^ (row & 7);
      gload16(w1t + (size_t)(n0 + row) * K1 + (t << 6) + (c << 3),
              Blds + (w * 32 + i * 8) * 64);
    }
    __syncthreads();

#pragma unroll
    for (int kk = 0; kk < 2; ++kk) {
      bf16x8 af[4], bfr[4];
#pragma unroll
      for (int m = 0; m < 4; ++m) {
        int row = wm * 64 + m * 16 + (l & 15);
        int c = (kk * 4 + (l >> 4)) ^ (row & 7);
        af[m] = *(const bf16x8*)(Alds + row * 64 + c * 8);
      }
#pragma unroll
      for (int n = 0; n < 4; ++n) {
        int row = wn * 64 + n * 16 + (l & 15);
        int c = (kk * 4 + (l >> 4)) ^ (row & 7);
        bfr[n] = *(const bf16x8*)(Blds + row * 64 + c * 8);
      }
#pragma unroll
      for (int m = 0; m < 4; ++m)
#pragma unroll
        for (int n = 0; n < 4; ++n)
          acc[m][n] = __builtin_amdgcn_mfma_f32_16x16x32_bf16(af[m], bfr[n], acc[m][n], 0, 0, 0);
    }
  }

  // epilogue: bias + relu -> bf16; n innermost => 128B contiguous per 16-lane group
  float bias0 = b1[n0 + wn * 64 + 0 * 16 + (l & 15)];
  float bias1 = b1[n0 + wn * 64 + 1 * 16 + (l & 15)];
  float bias2 = b1[n0 + wn * 64 + 2 * 16 + (l & 15)];
  float bias3 = b1[n0 + wn * 64 + 3 * 16 + (l & 15)];
#pragma unroll
  for (int m = 0; m < 4; ++m) {
#pragma unroll
    for (int q = 0; q < 4; ++q) {
      int gm = m0 + wm * 64 + m * 16 + (l >> 4) * 4 + q;
#pragma unroll
      for (int n = 0; n < 4; ++n) {
        float bias = n == 0 ? bias0 : n == 1 ? bias1 : n == 2 ? bias2 : bias3;
        int gn = n0 + wn * 64 + n * 16 + (l & 15);
        float v = acc[m][n][q] + bias;
        v = v > 0.f ? v : 0.f;
        hid[(size_t)gm * DIM + gn] = f2bf(v);
      }
    }
  }
}

// ---- GEMM2 (BN=256, 512 thr, hid read ONCE): out = hid @ W2 + b2 (f32) ----
__global__ __launch_bounds__(512, 2) void k_gemm2(
    const unsigned short* __restrict__ hid,   // [MPAD][256] bf16
    const unsigned short* __restrict__ w2t,   // [256][256] bf16 (W2^T)
    const float* __restrict__ b2,
    float* __restrict__ out)
{
  __shared__ __align__(16) unsigned short Alds[128 * 64];   // 16 KB
  __shared__ __align__(16) unsigned short Blds[256 * 64];   // 32 KB

  const int tid = threadIdx.x;
  const int w = tid >> 6, l = tid & 63;
  const int m0 = blockIdx.x * 128;
  const int wm = w >> 2, wn = w & 3;          // 2M x 4N waves, 64x64 each
  const int srow = l >> 3, slot = l & 7;

  f32x4 acc[4][4] = {};

  for (int t = 0; t < 4; ++t) {
    __syncthreads();
#pragma unroll
    for (int i = 0; i < 2; ++i) {             // A: 128 rows
      int row = w * 16 + i * 8 + srow;
      int c = slot ^ (row & 7);
      gload16(hid + (size_t)(m0 + row) * DIM + (t << 6) + (c << 3),
              Alds + (w * 16 + i * 8) * 64);
    }
#pragma unroll
    for (int i = 0; i < 4; ++i) {             // B: 256 rows
      int row = w * 32 + i * 8 + srow;
      int c = slot ^ (row & 7);
      gload16(w2t + (size_t)row * DIM + (t << 6) + (c << 3),
              Blds + (w * 32 + i * 8) * 64);
    }
    __syncthreads();

#pragma unroll
    for (int kk = 0; kk < 2; ++kk) {
      bf16x8 af[4], bfr[4];
#pragma unroll
      for (int m = 0; m < 4; ++m) {
        int row = wm * 64 + m * 16 + (l & 15);
        int c = (kk * 4 + (l >> 4)) ^ (row & 7);
        af[m] = *(const bf16x8*)(Alds + row * 64 + c * 8);
      }
#pragma unroll
      for (int n = 0; n < 4; ++n) {
        int row = wn * 64 + n * 16 + (l & 15);
        int c = (kk * 4 + (l >> 4)) ^ (row & 7);
        bfr[n] = *(const bf16x8*)(Blds + row * 64 + c * 8);
      }
#pragma unroll
      for (int m = 0; m < 4; ++m)
#pragma unroll
        for (int n = 0; n < 4; ++n)
          acc[m][n] = __builtin_amdgcn_mfma_f32_16x16x32_bf16(af[m], bfr[n], acc[m][n], 0, 0, 0);
    }
  }

  // epilogue: bias -> f32; n innermost => 256B contiguous per 16-lane group
  float bias0 = b2[wn * 64 + 0 * 16 + (l & 15)];
  float bias1 = b2[wn * 64 + 1 * 16 + (l & 15)];
  float bias2 = b2[wn * 64 + 2 * 16 + (l & 15)];
  float bias3 = b2[wn * 64 + 3 * 16 + (l & 15)];
#pragma unroll
  for (int m = 0; m < 4; ++m) {
#pragma unroll
    for (int q = 0; q < 4; ++q) {
      int gm = m0 + wm * 64 + m * 16 + (l >> 4) * 4 + q;
      if (gm < N_ABOVE) {
#pragma unroll
        for (int n = 0; n < 4; ++n) {
          float bias = n == 0 ? bias0 : n == 1 ? bias1 : n == 2 ? bias2 : bias3;
          int gn = wn * 64 + n * 16 + (l & 15);
          out[(size_t)gm * DIM + gn] = acc[m][n][q] + bias;
        }
      }
    }
  }
}

extern "C" void kernel_launch(void* const* d_in, const int* in_sizes, int n_in,
                              void* d_out, int out_size, void* d_ws, size_t ws_size,
                              hipStream_t stream) {
  const float* h    = (const float*)d_in[0];
  const int*   idx  = (const int*)d_in[2];
  const int*   jarr = (const int*)d_in[4];
  const float* W1   = (const float*)d_in[5];
  const float* b1   = (const float*)d_in[6];
  const float* W2   = (const float*)d_in[7];
  const float* b2   = (const float*)d_in[8];
  float* out = (float*)d_out;

  char* ws = (char*)d_ws;
  size_t off = 0;
  auto alloc = [&](size_t bytes) -> void* {
    void* p = ws + off;
    off += bytes;
    off = (off + 511) & ~(size_t)511;
    return p;
  };
  int*            inv = (int*)alloc((size_t)N_ABOVE * 4);
  unsigned short* hbf = (unsigned short*)alloc((size_t)(N_DOWN + 1) * DIM * 2);
  unsigned short* w1t = (unsigned short*)alloc((size_t)DIM * K1 * 2);
  unsigned short* w2t = (unsigned short*)alloc((size_t)DIM * DIM * 2);
  unsigned short* hid = (unsigned short*)alloc((size_t)MPAD * DIM * 2);
  if (ws_size < off) return;

  k_prep_inv<<<dim3(391), dim3(256), 0, stream>>>(inv, hbf);
  k_prep_all<<<dim3(12792), dim3(256), 0, stream>>>(h, idx, W1, W2, inv, hbf, w1t, w2t);
  k_gemm1<<<dim3(MPAD / 128, 2), dim3(256), 0, stream>>>(hbf, w1t, b1, inv, jarr, hid);
  k_gemm2<<<dim3(MPAD / 128), dim3(512), 0, stream>>>(hid, w2t, b2, out);
}